// Round 6
// baseline (324.808 us; speedup 1.0000x reference)
//
#include <hip/hip_runtime.h>
#include <hip/hip_bf16.h>

#define NN 8192
#define INF_ 512
#define OUTF 256

typedef __attribute__((ext_vector_type(8))) short short8;
typedef __attribute__((ext_vector_type(16))) float f32x16;

static __device__ __forceinline__ short f2bf(float x) {
  unsigned u = __float_as_uint(x);
  unsigned r = (u + 0x7fff + ((u >> 16) & 1)) >> 16;   // RNE to bf16
  return (short)r;
}
static __device__ __forceinline__ float bf2f(short s) {
  return __uint_as_float(((unsigned)(unsigned short)s) << 16);
}

// ---------------- Kernel 1: Wh = h @ W  (fp32, 64x128 tile, 512 thr) -------
// grid (128,2) = 256 blocks -> 1 block/CU (vs 128 blocks before: half idle).
// Reg-prefetch pipeline: next K-slab loads issued after barrier, drained by
// the barrier AFTER the FMA phase.
__global__ __launch_bounds__(512) void k_gemm_hW(const float* __restrict__ h,
                                                 const float* __restrict__ W,
                                                 float* __restrict__ Wh) {
  __shared__ float At[16][64];
  __shared__ float Bt[16][128];
  const int t = threadIdx.x;
  const int rb = blockIdx.x * 64;
  const int cb = blockIdx.y * 128;
  const int ar = t >> 3, ak = (t & 7) * 2;   // A stage: row, k-pair
  const int bk = t >> 5, bc = (t & 31) * 4;  // B stage: k-row, col
  const int tr = t >> 5, tc = t & 31;        // compute: 4 rows, 4 cols
  float acc[4][4];
#pragma unroll
  for (int i = 0; i < 4; ++i)
#pragma unroll
    for (int j = 0; j < 4; ++j) acc[i][j] = 0.f;

  float2 aval = *(const float2*)(h + (size_t)(rb + ar) * INF_ + ak);
  float4 bval = *(const float4*)(W + (size_t)bk * OUTF + cb + bc);

  for (int kb = 0; kb < INF_; kb += 16) {
    At[ak][ar] = aval.x;
    At[ak + 1][ar] = aval.y;
    *(float4*)&Bt[bk][bc] = bval;
    __syncthreads();
    if (kb + 16 < INF_) {
      aval = *(const float2*)(h + (size_t)(rb + ar) * INF_ + kb + 16 + ak);
      bval = *(const float4*)(W + (size_t)(kb + 16 + bk) * OUTF + cb + bc);
    }
#pragma unroll
    for (int k = 0; k < 16; ++k) {
      float4 a = *(const float4*)&At[k][tr * 4];
      float4 b = *(const float4*)&Bt[k][tc * 4];
      float av[4] = {a.x, a.y, a.z, a.w};
      float bv[4] = {b.x, b.y, b.z, b.w};
#pragma unroll
      for (int i = 0; i < 4; ++i)
#pragma unroll
        for (int j = 0; j < 4; ++j) acc[i][j] = fmaf(av[i], bv[j], acc[i][j]);
    }
    __syncthreads();
  }
#pragma unroll
  for (int i = 0; i < 4; ++i) {
    float* dst = &Wh[(size_t)(rb + tr * 4 + i) * OUTF + cb + tc * 4];
    *reinterpret_cast<float4*>(dst) = *reinterpret_cast<float4*>(&acc[i][0]);
  }
}

// ---------------- Kernel 1b: WhbT[col][row] = bf16(Wh[row][col]) -----------
__global__ __launch_bounds__(256) void k_transpose(const float* __restrict__ Wh,
                                                   short* __restrict__ WhbT) {
  __shared__ short tile[64][65];
  const int t = threadIdx.x;
  const int r0 = blockIdx.x * 64;
  const int c0 = blockIdx.y * 64;
  {
    const int ri = t >> 2, cq = t & 3;
    const float4* src = (const float4*)(Wh + (size_t)(r0 + ri) * OUTF + c0 + cq * 16);
#pragma unroll
    for (int q = 0; q < 4; ++q) {
      float4 v = src[q];
      int c = cq * 16 + q * 4;
      tile[ri][c + 0] = f2bf(v.x);
      tile[ri][c + 1] = f2bf(v.y);
      tile[ri][c + 2] = f2bf(v.z);
      tile[ri][c + 3] = f2bf(v.w);
    }
  }
  __syncthreads();
  {
    const int cj = t >> 2, rq = t & 3;
    short tmp[16];
#pragma unroll
    for (int q = 0; q < 16; ++q) tmp[q] = tile[rq * 16 + q][cj];
    short* dst = WhbT + (size_t)(c0 + cj) * NN + r0 + rq * 16;
    *(float4*)dst = *(float4*)&tmp[0];
    *(float4*)(dst + 8) = *(float4*)&tmp[8];
  }
}

// ---------------- Kernel 2: s/d per-row attention scalars ------------------
__global__ __launch_bounds__(256) void k_attn_sd(const float* __restrict__ Wh,
                                                 const float* __restrict__ a_src,
                                                 const float* __restrict__ a_dst,
                                                 float* __restrict__ sv,
                                                 float* __restrict__ dvv) {
  const int lane = threadIdx.x & 63;
  const int wave = threadIdx.x >> 6;
  const int row = blockIdx.x * 4 + wave;
  float4 wv = *reinterpret_cast<const float4*>(&Wh[(size_t)row * OUTF + lane * 4]);
  float4 as = *reinterpret_cast<const float4*>(&a_src[lane * 4]);
  float4 ad = *reinterpret_cast<const float4*>(&a_dst[lane * 4]);
  float ps = wv.x * as.x + wv.y * as.y + wv.z * as.z + wv.w * as.w;
  float pd = wv.x * ad.x + wv.y * ad.y + wv.z * ad.z + wv.w * ad.w;
#pragma unroll
  for (int off2 = 32; off2 > 0; off2 >>= 1) {
    ps += __shfl_down(ps, off2);
    pd += __shfl_down(pd, off2);
  }
  if (lane == 0) {
    sv[row] = ps;
    dvv[row] = pd;
  }
}

// ---------------- Kernel 3: fused mask+softmax(unnorm)+PV via MFMA ---------
// 64x256 tile/block, 4 waves (32x128 each), j-step 64, S j-splits.
// Software pipeline: regs for tile t were loaded during tile t-1's MFMA
// phase; barrier-2 (compiler's vmcnt(0) drain) is the natural wait point.
__global__ __launch_bounds__(256) void k_attn_pv(const int* __restrict__ adj,
                                                 const short* __restrict__ WhbT,
                                                 const float* __restrict__ sv,
                                                 const float* __restrict__ dv,
                                                 float* __restrict__ accP,
                                                 float* __restrict__ zP,
                                                 int jspan) {
  __shared__ short Vt[256 * 64];   // [col][k], rows 128B, XOR-swizzled (32 KB)
  __shared__ short Pl[64 * 64];    // [row][k], rows 128B, XOR-swizzled (8 KB)
  const int t = threadIdx.x;
  const int rb = blockIdx.x * 64;
  const int pr = t >> 2;           // P-gen row
  const int pq = t & 3;            // P-gen 16-wide j-chunk
  const float s_i = sv[rb + pr];
  const int lane = t & 63;
  const int wid = t >> 6;
  const int l31 = lane & 31;
  const int lhi = lane >> 5;
  const int wrow = (wid >> 1) * 32;
  const int wcol = (wid & 1) * 128;
  char* VtB = (char*)Vt;
  char* PlB = (char*)Pl;
  const int arow = wrow + l31;
  const int abase = arow * 128 + lhi * 16;
  const int aswz = (arow & 7) << 4;
  const int pbyte = pr * 128 + pq * 32;
  const int pswz = (pr & 7) << 4;
  const int vswz = (t & 7) << 4;

  f32x16 acc[4];
#pragma unroll
  for (int ct = 0; ct < 4; ++ct) acc[ct] = (f32x16)(0.f);
  float zacc = 0.f;

  const int j0 = blockIdx.y * jspan;
  const int iters = jspan >> 6;

  // ---- prologue: load tile-0 operands into registers ----
  float4 vreg[8];
  int4 areg[4];
  float4 dreg[4];
  {
    const float4* vsrc = (const float4*)(WhbT + (size_t)t * NN + j0);
#pragma unroll
    for (int s = 0; s < 8; ++s) vreg[s] = vsrc[s];
    const int4* aptr = (const int4*)(adj + (size_t)(rb + pr) * NN + j0 + pq * 16);
#pragma unroll
    for (int q = 0; q < 4; ++q) areg[q] = aptr[q];
    const float4* dptr = (const float4*)(dv + j0 + pq * 16);
#pragma unroll
    for (int q = 0; q < 4; ++q) dreg[q] = dptr[q];
  }

  for (int it = 0; it < iters; ++it) {
    // ---- P-gen from regs: w = adj ? exp(lrelu(s_i + d_j)) : 0 (bf16) ----
    alignas(16) short wb[16];
#pragma unroll
    for (int q = 0; q < 4; ++q) {
      float ev[4] = {dreg[q].x, dreg[q].y, dreg[q].z, dreg[q].w};
      int av[4] = {areg[q].x, areg[q].y, areg[q].z, areg[q].w};
#pragma unroll
      for (int u = 0; u < 4; ++u) {
        float e = s_i + ev[u];
        e = e >= 0.f ? e : 0.2f * e;
        float w = av[u] > 0 ? __expf(e) : 0.f;
        short b = f2bf(w);
        wb[q * 4 + u] = b;
        zacc += bf2f(b);
      }
    }
    *(float4*)(PlB + (pbyte ^ pswz)) = *(float4*)&wb[0];
    *(float4*)(PlB + ((pbyte + 16) ^ pswz)) = *(float4*)&wb[8];
    // ---- Vt writes from regs (swizzled; 8 slots evenly covered) ----
#pragma unroll
    for (int s = 0; s < 8; ++s)
      *(float4*)(VtB + ((t * 128 + s * 16) ^ vswz)) = vreg[s];
    __syncthreads();
    // ---- issue NEXT tile's global loads (in flight across MFMA phase) ----
    if (it + 1 < iters) {
      const int jn = j0 + (it + 1) * 64;
      const float4* vsrc = (const float4*)(WhbT + (size_t)t * NN + jn);
#pragma unroll
      for (int s = 0; s < 8; ++s) vreg[s] = vsrc[s];
      const int4* aptr = (const int4*)(adj + (size_t)(rb + pr) * NN + jn + pq * 16);
#pragma unroll
      for (int q = 0; q < 4; ++q) areg[q] = aptr[q];
      const float4* dptr = (const float4*)(dv + jn + pq * 16);
#pragma unroll
      for (int q = 0; q < 4; ++q) dreg[q] = dptr[q];
    }
    // ---- MFMA: wave tile 32x128, 4 k-slices of 16 ----
#pragma unroll
    for (int ks = 0; ks < 4; ++ks) {
      short8 af = *(const short8*)(PlB + ((abase + ks * 32) ^ aswz));
#pragma unroll
      for (int ct = 0; ct < 4; ++ct) {
        const int c = wcol + ct * 32 + l31;
        short8 bf = *(const short8*)(VtB + ((c * 128 + ks * 32 + lhi * 16) ^ ((c & 7) << 4)));
        acc[ct] = __builtin_amdgcn_mfma_f32_32x32x16_bf16(af, bf, acc[ct], 0, 0, 0);
      }
    }
    __syncthreads();   // compiler drains vmcnt(0): prefetch lands here
  }
  // ---- z: reduce 4 lanes (same row) via shfl, no LDS ----
  float z2 = zacc + __shfl_xor(zacc, 1, 64);
  z2 += __shfl_xor(z2, 2, 64);
  if (pq == 0) zP[blockIdx.y * NN + rb + pr] = z2;
  // ---- acc epilogue ----
  const size_t slab = (size_t)blockIdx.y * NN * OUTF;
#pragma unroll
  for (int ct = 0; ct < 4; ++ct) {
#pragma unroll
    for (int q = 0; q < 16; ++q) {
      const int row = rb + wrow + 4 * lhi + (q & 3) + 8 * (q >> 2);
      const int col = wcol + ct * 32 + l31;
      accP[slab + (size_t)row * OUTF + col] = acc[ct][q];
    }
  }
}

// ---------------- Kernel 4: combine partials, normalize --------------------
__global__ __launch_bounds__(256) void k_reduce(const float* __restrict__ accP,
                                                const float* __restrict__ zP,
                                                float* __restrict__ out, int S) {
  const int row = blockIdx.x;
  const int f = threadIdx.x;
  const size_t idx = (size_t)row * OUTF + f;
  float a = 0.f, z = 0.f;
  for (int s = 0; s < S; ++s) {
    a += accP[(size_t)s * NN * OUTF + idx];
    z += zP[s * NN + row];
  }
  out[idx] = a / z;
}

extern "C" void kernel_launch(void* const* d_in, const int* in_sizes, int n_in,
                              void* d_out, int out_size, void* d_ws, size_t ws_size,
                              hipStream_t stream) {
  const float* h = (const float*)d_in[0];
  const int* adj = (const int*)d_in[1];
  const float* W = (const float*)d_in[2];
  const float* a_src = (const float*)d_in[3];
  const float* a_dst = (const float*)d_in[4];
  float* out = (float*)d_out;

  char* ws = (char*)d_ws;
  float* Wh = (float*)ws;                                    // 8 MB
  short* WhbT = (short*)(ws + (size_t)NN * OUTF * 4);        // 4 MB
  float* sv = (float*)(ws + (size_t)NN * OUTF * 6);          // 32 KB
  float* dvv = sv + NN;                                      // 32 KB
  float* zP = dvv + NN;                                      // 8*32 KB
  size_t off = (size_t)NN * OUTF * 6 + 2 * (size_t)NN * 4 + 8 * (size_t)NN * 4;
  off = (off + 255) & ~(size_t)255;
  const size_t slab_bytes = (size_t)NN * OUTF * 4;
  int S;
  float* accP;
  if (ws_size >= off + 8 * slab_bytes) { S = 8; accP = (float*)(ws + off); }
  else if (ws_size >= off + 4 * slab_bytes) { S = 4; accP = (float*)(ws + off); }
  else if (ws_size >= off + 2 * slab_bytes) { S = 2; accP = (float*)(ws + off); }
  else if (ws_size >= off + 1 * slab_bytes) { S = 1; accP = (float*)(ws + off); }
  else { S = 1; accP = out; }   // fallback: accumulate into out, normalize in place

  k_gemm_hW<<<dim3(NN / 64, OUTF / 128), dim3(512), 0, stream>>>(h, W, Wh);
  k_transpose<<<dim3(NN / 64, OUTF / 64), dim3(256), 0, stream>>>(Wh, WhbT);
  k_attn_sd<<<dim3(NN / 4), dim3(256), 0, stream>>>(Wh, a_src, a_dst, sv, dvv);
  k_attn_pv<<<dim3(NN / 64, S), dim3(256), 0, stream>>>(adj, WhbT, sv, dvv, accP, zP, NN / S);
  k_reduce<<<dim3(NN), dim3(256), 0, stream>>>(accP, zP, out, S);
}

// Round 7
// 150.434 us; speedup vs baseline: 2.1591x; 2.1591x over previous
//
#include <hip/hip_runtime.h>
#include <hip/hip_bf16.h>

#define NN 8192
#define INF_ 512
#define OUTF 256

typedef __attribute__((ext_vector_type(8))) short short8;
typedef __attribute__((ext_vector_type(16))) float f32x16;

static __device__ __forceinline__ short f2bf(float x) {
  unsigned u = __float_as_uint(x);
  unsigned r = (u + 0x7fff + ((u >> 16) & 1)) >> 16;   // RNE to bf16
  return (short)r;
}
static __device__ __forceinline__ float bf2f(short s) {
  return __uint_as_float(((unsigned)(unsigned short)s) << 16);
}
// async global->LDS, 16B per lane; LDS dest = wave-uniform base + lane*16
static __device__ __forceinline__ void gl2lds16(const short* g, short* l) {
  __builtin_amdgcn_global_load_lds(
      (const __attribute__((address_space(1))) unsigned int*)g,
      (__attribute__((address_space(3))) unsigned int*)l, 16, 0, 0);
}

// ---------------- Kernel 1: Wh = h @ W  (fp32, 64x128 tile, 512 thr) -------
__global__ __launch_bounds__(512) void k_gemm_hW(const float* __restrict__ h,
                                                 const float* __restrict__ W,
                                                 float* __restrict__ Wh) {
  __shared__ float At[16][64];
  __shared__ float Bt[16][128];
  const int t = threadIdx.x;
  const int rb = blockIdx.x * 64;
  const int cb = blockIdx.y * 128;
  const int ar = t >> 3, ak = (t & 7) * 2;   // A stage: row, k-pair
  const int bk = t >> 5, bc = (t & 31) * 4;  // B stage: k-row, col
  const int tr = t >> 5, tc = t & 31;        // compute: 4 rows, 4 cols
  float acc[4][4];
#pragma unroll
  for (int i = 0; i < 4; ++i)
#pragma unroll
    for (int j = 0; j < 4; ++j) acc[i][j] = 0.f;

  float2 aval = *(const float2*)(h + (size_t)(rb + ar) * INF_ + ak);
  float4 bval = *(const float4*)(W + (size_t)bk * OUTF + cb + bc);

  for (int kb = 0; kb < INF_; kb += 16) {
    At[ak][ar] = aval.x;
    At[ak + 1][ar] = aval.y;
    *(float4*)&Bt[bk][bc] = bval;
    __syncthreads();
    if (kb + 16 < INF_) {
      aval = *(const float2*)(h + (size_t)(rb + ar) * INF_ + kb + 16 + ak);
      bval = *(const float4*)(W + (size_t)(kb + 16 + bk) * OUTF + cb + bc);
    }
#pragma unroll
    for (int k = 0; k < 16; ++k) {
      float4 a = *(const float4*)&At[k][tr * 4];
      float4 b = *(const float4*)&Bt[k][tc * 4];
      float av[4] = {a.x, a.y, a.z, a.w};
      float bv[4] = {b.x, b.y, b.z, b.w};
#pragma unroll
      for (int i = 0; i < 4; ++i)
#pragma unroll
        for (int j = 0; j < 4; ++j) acc[i][j] = fmaf(av[i], bv[j], acc[i][j]);
    }
    __syncthreads();
  }
#pragma unroll
  for (int i = 0; i < 4; ++i) {
    float* dst = &Wh[(size_t)(rb + tr * 4 + i) * OUTF + cb + tc * 4];
    *reinterpret_cast<float4*>(dst) = *reinterpret_cast<float4*>(&acc[i][0]);
  }
}

// ---------------- Kernel 1b: WhbT[col][row] = bf16(Wh[row][col]) -----------
__global__ __launch_bounds__(256) void k_transpose(const float* __restrict__ Wh,
                                                   short* __restrict__ WhbT) {
  __shared__ short tile[64][65];
  const int t = threadIdx.x;
  const int r0 = blockIdx.x * 64;
  const int c0 = blockIdx.y * 64;
  {
    const int ri = t >> 2, cq = t & 3;
    const float4* src = (const float4*)(Wh + (size_t)(r0 + ri) * OUTF + c0 + cq * 16);
#pragma unroll
    for (int q = 0; q < 4; ++q) {
      float4 v = src[q];
      int c = cq * 16 + q * 4;
      tile[ri][c + 0] = f2bf(v.x);
      tile[ri][c + 1] = f2bf(v.y);
      tile[ri][c + 2] = f2bf(v.z);
      tile[ri][c + 3] = f2bf(v.w);
    }
  }
  __syncthreads();
  {
    const int cj = t >> 2, rq = t & 3;
    short tmp[16];
#pragma unroll
    for (int q = 0; q < 16; ++q) tmp[q] = tile[rq * 16 + q][cj];
    short* dst = WhbT + (size_t)(c0 + cj) * NN + r0 + rq * 16;
    *(float4*)dst = *(float4*)&tmp[0];
    *(float4*)(dst + 8) = *(float4*)&tmp[8];
  }
}

// ---------------- Kernel 2: s/d per-row attention scalars ------------------
__global__ __launch_bounds__(256) void k_attn_sd(const float* __restrict__ Wh,
                                                 const float* __restrict__ a_src,
                                                 const float* __restrict__ a_dst,
                                                 float* __restrict__ sv,
                                                 float* __restrict__ dvv) {
  const int lane = threadIdx.x & 63;
  const int wave = threadIdx.x >> 6;
  const int row = blockIdx.x * 4 + wave;
  float4 wv = *reinterpret_cast<const float4*>(&Wh[(size_t)row * OUTF + lane * 4]);
  float4 as = *reinterpret_cast<const float4*>(&a_src[lane * 4]);
  float4 ad = *reinterpret_cast<const float4*>(&a_dst[lane * 4]);
  float ps = wv.x * as.x + wv.y * as.y + wv.z * as.z + wv.w * as.w;
  float pd = wv.x * ad.x + wv.y * ad.y + wv.z * ad.z + wv.w * ad.w;
#pragma unroll
  for (int off2 = 32; off2 > 0; off2 >>= 1) {
    ps += __shfl_down(ps, off2);
    pd += __shfl_down(pd, off2);
  }
  if (lane == 0) {
    sv[row] = ps;
    dvv[row] = pd;
  }
}

// ---------------- Kernel 3: fused mask+softmax(unnorm)+PV via MFMA ---------
// 64x256 tile/block, 4 waves (32x128), j-step 64.
// V staged via global_load_lds into double-buffered Vt (zero VGPR staging);
// source addresses pre-swizzled so linear DMA writes produce the XOR-swizzled
// layout. adj/dv reg-prefetched 2 tiles ahead (A/B ping-pong, static index).
__global__ __launch_bounds__(256) void k_attn_pv(const int* __restrict__ adj,
                                                 const short* __restrict__ WhbT,
                                                 const float* __restrict__ sv,
                                                 const float* __restrict__ dv,
                                                 float* __restrict__ accP,
                                                 float* __restrict__ zP,
                                                 int jspan) {
  __shared__ short Vt0[256 * 64];  // 32 KB, [col][k] rows 128B, XOR-swizzled
  __shared__ short Vt1[256 * 64];  // 32 KB, second buffer
  __shared__ short Pl[64 * 64];    // 8 KB, [row][k] rows 128B, XOR-swizzled
  const int t = threadIdx.x;
  const int rb = blockIdx.x * 64;
  const int pr = t >> 2;           // P-gen row
  const int pq = t & 3;            // P-gen 16-wide j-chunk
  const float s_i = sv[rb + pr];
  const int lane = t & 63;
  const int wid = t >> 6;
  const int l31 = lane & 31;
  const int lhi = lane >> 5;
  const int wrow = (wid >> 1) * 32;
  const int wcol = (wid & 1) * 128;
  char* PlB = (char*)Pl;
  const int arow = wrow + l31;
  const int abase = arow * 128 + lhi * 16;
  const int aswz = (arow & 7) << 4;
  const int pbyte = pr * 128 + pq * 32;
  const int pswz = (pr & 7) << 4;
  // V staging geometry: instr r of wave w covers rows 64w+8r..+8; lane l ->
  // row 64w+8r+(l>>3), phys slot l&7; content chunk = (l&7)^((l>>3)&7)
  // (row&7 == (l>>3)&7 since 64w+8r = 0 mod 8) -> source pre-swizzle.
  const int vrow0 = wid * 64 + (lane >> 3);
  const int vchunk = ((lane & 7) ^ ((lane >> 3) & 7)) * 8;
  const short* vsrc0 = WhbT + (size_t)vrow0 * NN + vchunk;
  short* vdst0 = Vt0 + wid * 4096;   // + r*512 (shorts), wave-uniform
  short* vdst1 = Vt1 + wid * 4096;

  f32x16 acc[4];
#pragma unroll
  for (int ct = 0; ct < 4; ++ct) acc[ct] = (f32x16)(0.f);
  float zacc = 0.f;

  const int j0 = blockIdx.y * jspan;
  const int iters = jspan >> 6;    // always even (16/32/64/128)

#define ISSUE_V(JB, VDST)                                                     \
  _Pragma("unroll")                                                           \
  for (int r = 0; r < 8; ++r)                                                 \
    gl2lds16(vsrc0 + (JB) + r * 8 * NN, (VDST) + r * 512);

#define LOAD_AD(JB, AR, DR)                                                   \
  {                                                                           \
    const int4* ap = (const int4*)(adj + (size_t)(rb + pr) * NN + (JB) + pq * 16); \
    _Pragma("unroll") for (int q = 0; q < 4; ++q) AR[q] = ap[q];              \
    const float4* dp = (const float4*)(dv + (JB) + pq * 16);                  \
    _Pragma("unroll") for (int q = 0; q < 4; ++q) DR[q] = dp[q];              \
  }

#define PGEN_STORE(AR, DR)                                                    \
  {                                                                           \
    alignas(16) short wb[16];                                                 \
    _Pragma("unroll")                                                         \
    for (int q = 0; q < 4; ++q) {                                             \
      float ev[4] = {DR[q].x, DR[q].y, DR[q].z, DR[q].w};                     \
      int av[4] = {AR[q].x, AR[q].y, AR[q].z, AR[q].w};                       \
      _Pragma("unroll")                                                       \
      for (int u = 0; u < 4; ++u) {                                           \
        float e = s_i + ev[u];                                                \
        e = e >= 0.f ? e : 0.2f * e;                                          \
        float w = av[u] > 0 ? __expf(e) : 0.f;                                \
        short b = f2bf(w);                                                    \
        wb[q * 4 + u] = b;                                                    \
        zacc += bf2f(b);                                                      \
      }                                                                       \
    }                                                                         \
    *(float4*)(PlB + (pbyte ^ pswz)) = *(float4*)&wb[0];                      \
    *(float4*)(PlB + ((pbyte + 16) ^ pswz)) = *(float4*)&wb[8];               \
  }

#define MFMA_PHASE(VTB)                                                       \
  _Pragma("unroll")                                                           \
  for (int ks = 0; ks < 4; ++ks) {                                            \
    short8 af = *(const short8*)(PlB + ((abase + ks * 32) ^ aswz));           \
    _Pragma("unroll")                                                         \
    for (int ct = 0; ct < 4; ++ct) {                                          \
      const int c = wcol + ct * 32 + l31;                                     \
      short8 bf = *(const short8*)((char*)(VTB) +                             \
                    ((c * 128 + ks * 32 + lhi * 16) ^ ((c & 7) << 4)));       \
      acc[ct] = __builtin_amdgcn_mfma_f32_32x32x16_bf16(af, bf, acc[ct], 0, 0, 0); \
    }                                                                         \
  }

  // ---- prologue: adj/dv for tiles 0,1 -> regs; V(0) -> Vt0 ----
  int4 aA[4], aB[4];
  float4 dA[4], dB[4];
  LOAD_AD(j0, aA, dA);
  LOAD_AD(j0 + 64, aB, dB);
  ISSUE_V(j0, vdst0);

  for (int it = 0; it < iters; it += 2) {
    const int jb = j0 + it * 64;
    // ---- even sub-iter: consume A + Vt0 ----
    PGEN_STORE(aA, dA);
    __syncthreads();                       // V(it) landed (drained here/prev)
    ISSUE_V(jb + 64, vdst1);               // V(it+1), flies across MFMA
    if (it + 2 < iters) LOAD_AD(jb + 128, aA, dA);   // adj(it+2), 2-deep
    MFMA_PHASE(Vt0);
    __syncthreads();                       // drains vmcnt: V(it+1)/adj ready
    // ---- odd sub-iter: consume B + Vt1 ----
    PGEN_STORE(aB, dB);
    __syncthreads();
    if (it + 2 < iters) ISSUE_V(jb + 128, vdst0);    // V(it+2)
    if (it + 3 < iters) LOAD_AD(jb + 192, aB, dB);   // adj(it+3)
    MFMA_PHASE(Vt1);
    __syncthreads();
  }
#undef ISSUE_V
#undef LOAD_AD
#undef PGEN_STORE
#undef MFMA_PHASE

  // ---- z: reduce 4 lanes (same row) via shfl ----
  float z2 = zacc + __shfl_xor(zacc, 1, 64);
  z2 += __shfl_xor(z2, 2, 64);
  if (pq == 0) zP[blockIdx.y * NN + rb + pr] = z2;
  // ---- acc epilogue ----
  const size_t slab = (size_t)blockIdx.y * NN * OUTF;
#pragma unroll
  for (int ct = 0; ct < 4; ++ct) {
#pragma unroll
    for (int q = 0; q < 16; ++q) {
      const int row = rb + wrow + 4 * lhi + (q & 3) + 8 * (q >> 2);
      const int col = wcol + ct * 32 + l31;
      accP[slab + (size_t)row * OUTF + col] = acc[ct][q];
    }
  }
}

// ---------------- Kernel 4: combine partials, normalize --------------------
__global__ __launch_bounds__(256) void k_reduce(const float* __restrict__ accP,
                                                const float* __restrict__ zP,
                                                float* __restrict__ out, int S) {
  const int row = blockIdx.x;
  const int f = threadIdx.x;
  const size_t idx = (size_t)row * OUTF + f;
  float a = 0.f, z = 0.f;
  for (int s = 0; s < S; ++s) {
    a += accP[(size_t)s * NN * OUTF + idx];
    z += zP[s * NN + row];
  }
  out[idx] = a / z;
}

extern "C" void kernel_launch(void* const* d_in, const int* in_sizes, int n_in,
                              void* d_out, int out_size, void* d_ws, size_t ws_size,
                              hipStream_t stream) {
  const float* h = (const float*)d_in[0];
  const int* adj = (const int*)d_in[1];
  const float* W = (const float*)d_in[2];
  const float* a_src = (const float*)d_in[3];
  const float* a_dst = (const float*)d_in[4];
  float* out = (float*)d_out;

  char* ws = (char*)d_ws;
  float* Wh = (float*)ws;                                    // 8 MB
  short* WhbT = (short*)(ws + (size_t)NN * OUTF * 4);        // 4 MB
  float* sv = (float*)(ws + (size_t)NN * OUTF * 6);          // 32 KB
  float* dvv = sv + NN;                                      // 32 KB
  float* zP = dvv + NN;                                      // 8*32 KB
  size_t off = (size_t)NN * OUTF * 6 + 2 * (size_t)NN * 4 + 8 * (size_t)NN * 4;
  off = (off + 255) & ~(size_t)255;
  const size_t slab_bytes = (size_t)NN * OUTF * 4;
  int S;
  float* accP;
  if (ws_size >= off + 4 * slab_bytes) { S = 4; accP = (float*)(ws + off); }      // preferred: 512 blocks, half the partial traffic of S=8
  else if (ws_size >= off + 2 * slab_bytes) { S = 2; accP = (float*)(ws + off); }
  else if (ws_size >= off + 1 * slab_bytes) { S = 1; accP = (float*)(ws + off); }
  else { S = 1; accP = out; }   // fallback: accumulate into out, normalize in place

  k_gemm_hW<<<dim3(NN / 64, OUTF / 128), dim3(512), 0, stream>>>(h, W, Wh);
  k_transpose<<<dim3(NN / 64, OUTF / 64), dim3(256), 0, stream>>>(Wh, WhbT);
  k_attn_sd<<<dim3(NN / 4), dim3(256), 0, stream>>>(Wh, a_src, a_dst, sv, dvv);
  k_attn_pv<<<dim3(NN / 64, S), dim3(256), 0, stream>>>(adj, WhbT, sv, dvv, accP, zP, NN / S);
  k_reduce<<<dim3(NN), dim3(256), 0, stream>>>(accP, zP, out, S);
}